// Round 1
// baseline (8830.234 us; speedup 1.0000x reference)
//
#include <hip/hip_runtime.h>
#include <cmath>

// ---------------------------------------------------------------------------
// RQ-VAE forward, fp32 baseline.
// Pipeline: enc1..enc4 (tiled direct conv) -> transpose -> 4x residual-VQ
// (fused GEMM+argmin) -> quantized -> dec1 conv -> 3x convT (parity-decomposed
// into 4 k=2 s=1 convs each) -> recon(tanh).
// Workspace layout (floats), total 84,089,856 f = 336.4 MB:
//   F0 [0)        16,777,216 : h1, later z, later d2
//   F1 [16777216)  8,388,608 : h2, later d1 ; d3 spans [16777216, 83886080)
//   F2 [25165824) 16,777,216 : h3, later zt
//   F3 [41943040) 16,777,216 : residual
//   FW [83886080) : parity weights wp2/wp3/wp4 + codebook norms
// ---------------------------------------------------------------------------

// ---------------- row vector load from LDS (aligned) ----------------
template<int RW>
__device__ __forceinline__ void load_row(const float* __restrict__ p, float* r) {
  if constexpr (RW == 5) {
    float4 a = *(const float4*)p;
    r[0]=a.x; r[1]=a.y; r[2]=a.z; r[3]=a.w; r[4]=p[4];
  } else if constexpr (RW == 6) {
    float4 a = *(const float4*)p; float2 b = *(const float2*)(p+4);
    r[0]=a.x; r[1]=a.y; r[2]=a.z; r[3]=a.w; r[4]=b.x; r[5]=b.y;
  } else if constexpr (RW == 10) {
    float4 a = *(const float4*)p; float4 b = *(const float4*)(p+4);
    float2 c = *(const float2*)(p+8);
    r[0]=a.x; r[1]=a.y; r[2]=a.z; r[3]=a.w;
    r[4]=b.x; r[5]=b.y; r[6]=b.z; r[7]=b.w; r[8]=c.x; r[9]=c.y;
  }
}

// ---------------- generic tiled direct conv ----------------
// OCT=64: 16 oc-lanes x 4 oc each (float4 weight reads), 8x8 spatial tile,
//         each thread 4 consecutive ox.
// OCT=4 : 4 oc-lanes x 1 oc, 16x16 spatial tile (for Cout=3 decoder head).
// Output addressing is fully strided so the same kernel writes NCHW or
// parity-interleaved convT outputs.
template<int OCT, int SPTH, int SPTW, int KH, int KW, int S, int ACT>
__global__ __launch_bounds__(256) void conv_tiled(
    const float* __restrict__ in, const float* __restrict__ wgt,
    const float* __restrict__ bias, float* __restrict__ out,
    int N, int Cin, int Hin, int Win, int Cout, int WT,
    int padY, int padX,
    long outBase, long outNStride, long outCStride, long outYStride, long outXStride)
{
  constexpr int CK   = 8;
  constexpr int IH   = (SPTH-1)*S + KH;
  constexpr int IWr  = (SPTW-1)*S + KW;
  constexpr int IW   = (IWr + 3) & ~3;          // pad row to x4 for b128 loads
  constexpr int TAPS = KH*KW;
  constexpr int WST  = (OCT==64) ? 68 : 5;      // weight LDS stride (align+banks)
  constexpr int LOC  = (OCT==64) ? 16 : 4;      // oc lanes
  constexpr int OPT  = OCT/LOC;                 // oc per thread
  constexpr int RW   = 3*S + KW;                // input row regs per thread
  constexpr int EPW  = (OCT==64) ? 65 : 257;    // epilogue LDS row stride
  constexpr int SP   = SPTH*SPTW;
  constexpr int STG  = CK*IH*IW + CK*TAPS*WST;
  constexpr int SMEMN = (STG > OCT*EPW) ? STG : OCT*EPW;
  __shared__ float smem[SMEMN];
  float* s_in = smem;
  float* s_w  = smem + CK*IH*IW;

  const int tid  = threadIdx.x;
  const int tile = blockIdx.x, ocb = blockIdx.y, n = blockIdx.z;
  const int oy0 = (tile / WT) * SPTH, ox0 = (tile % WT) * SPTW;
  const int ol  = tid % LOC;
  const int g   = tid / LOC;
  const int s0  = g * 4;
  const int sy  = s0 / SPTW, sx0 = s0 % SPTW;
  const int iy0 = oy0*S - padY, ix0 = ox0*S - padX;

  float acc[OPT][4];
#pragma unroll
  for (int o = 0; o < OPT; ++o)
#pragma unroll
    for (int j = 0; j < 4; ++j) acc[o][j] = 0.f;

  for (int c0 = 0; c0 < Cin; c0 += CK) {
    __syncthreads();
    // stage input patch (zero-filled for pad / channel tail)
    for (int i = tid; i < CK*IH*IW; i += 256) {
      int c = i / (IH*IW), r2 = i % (IH*IW);
      int iy = r2 / IW, ix = r2 % IW;
      int gy = iy0 + iy, gx = ix0 + ix;
      float v = 0.f;
      if (c0 + c < Cin && (unsigned)gy < (unsigned)Hin && (unsigned)gx < (unsigned)Win)
        v = in[(((long)n*Cin + c0 + c)*Hin + gy)*Win + gx];
      s_in[i] = v;
    }
    // stage weights as [c][tap][oc] (stride WST)
    for (int i = tid; i < OCT*CK*TAPS; i += 256) {
      int o = i / (CK*TAPS), ct = i % (CK*TAPS);
      int oc = ocb*OCT + o, ci = c0 + ct / TAPS;
      float v = 0.f;
      if (oc < Cout && ci < Cin)
        v = wgt[((long)oc*Cin + ci)*TAPS + (ct % TAPS)];
      s_w[ct*WST + o] = v;
    }
    __syncthreads();

    for (int c = 0; c < CK; ++c) {
#pragma unroll
      for (int ky = 0; ky < KH; ++ky) {
        float r[RW];
        load_row<RW>(&s_in[c*(IH*IW) + (sy*S + ky)*IW + sx0*S], r);
#pragma unroll
        for (int kx = 0; kx < KW; ++kx) {
          if constexpr (OCT == 64) {
            float4 w4 = *(const float4*)&s_w[(c*TAPS + ky*KW + kx)*WST + ol*4];
            float wv[4] = {w4.x, w4.y, w4.z, w4.w};
#pragma unroll
            for (int o = 0; o < 4; ++o)
#pragma unroll
              for (int j = 0; j < 4; ++j)
                acc[o][j] = fmaf(wv[o], r[j*S + kx], acc[o][j]);
          } else {
            float w = s_w[(c*TAPS + ky*KW + kx)*WST + ol];
#pragma unroll
            for (int j = 0; j < 4; ++j)
              acc[0][j] = fmaf(w, r[j*S + kx], acc[0][j]);
          }
        }
      }
    }
  }

  // epilogue: bias+act, LDS transpose, semi-coalesced store
  __syncthreads();
#pragma unroll
  for (int o = 0; o < OPT; ++o) {
    int oc = ocb*OCT + ol*OPT + o;
    float b = (oc < Cout) ? bias[oc] : 0.f;
#pragma unroll
    for (int j = 0; j < 4; ++j) {
      float v = acc[o][j] + b;
      if constexpr (ACT == 1) v = fmaxf(v, 0.f);
      else if constexpr (ACT == 2) v = tanhf(v);
      smem[(ol*OPT + o)*EPW + s0 + j] = v;
    }
  }
  __syncthreads();
  for (int i = tid; i < OCT*SP; i += 256) {
    int o = i / SP, sp = i % SP;
    int oc = ocb*OCT + o;
    if (oc < Cout) {
      int syy = sp / SPTW, sxx = sp % SPTW;
      long off = outBase + (long)n*outNStride + (long)oc*outCStride
               + (long)(oy0 + syy)*outYStride + (long)(ox0 + sxx)*outXStride;
      out[off] = smem[o*EPW + sp];
    }
  }
}

// ---------------- convT weight rearrange into 4 parity 2x2 convs ------------
// wp[p][oc][ic][d][e] = W[ic][oc][ky(py,d)][kx(px,e)], p = py*2+px
__global__ void rearrange_convT(const float* __restrict__ w, float* __restrict__ wp,
                                int Cin, int Cout) {
  int total = 4*Cout*Cin*4;
  for (int idx = blockIdx.x*256 + threadIdx.x; idx < total; idx += gridDim.x*256) {
    int e = idx & 1, d = (idx >> 1) & 1;
    int r = idx >> 2;
    int ic = r % Cin; r /= Cin;
    int oc = r % Cout; int p = r / Cout;
    int py = p >> 1, px = p & 1;
    int ky = py ? (d ? 0 : 2) : (d ? 1 : 3);
    int kx = px ? (e ? 0 : 2) : (e ? 1 : 3);
    wp[idx] = w[((ic*Cout + oc)*4 + ky)*4 + kx];
  }
}

// ---------------- codebook squared norms ----------------
__global__ __launch_bounds__(256) void cb_norm(const float* __restrict__ cb,
                                               float* __restrict__ outn) {
  int row = blockIdx.x;
  float v = cb[(long)row*256 + threadIdx.x];
  v *= v;
  for (int off = 32; off; off >>= 1) v += __shfl_down(v, off, 64);
  __shared__ float sr[4];
  if ((threadIdx.x & 63) == 0) sr[threadIdx.x >> 6] = v;
  __syncthreads();
  if (threadIdx.x == 0) outn[row] = sr[0] + sr[1] + sr[2] + sr[3];
}

__global__ void zero4(float* __restrict__ p) {
  if (threadIdx.x < 4) p[threadIdx.x] = 0.f;
}

// ---------------- z (NCHW) -> token-major zt + residual copy ----------------
__global__ __launch_bounds__(256) void transpose_zt(const float* __restrict__ z,
                                                    float* __restrict__ zt,
                                                    float* __restrict__ res) {
  __shared__ float t[32][33];
  int b = blockIdx.z, c0 = blockIdx.y*32, hw0 = blockIdx.x*32;
  for (int i = threadIdx.x; i < 1024; i += 256) {
    int cc = i >> 5, ww = i & 31;
    t[cc][ww] = z[((long)(b*256 + c0 + cc) << 12) + hw0 + ww];
  }
  __syncthreads();
  for (int i = threadIdx.x; i < 1024; i += 256) {
    int ww = i >> 5, cc = i & 31;
    float v = t[cc][ww];
    long o = ((long)(b*4096 + hw0 + ww) << 8) + c0 + cc;
    zt[o] = v; res[o] = v;
  }
}

// ---------------- quantized = zt - residual, token-major -> NCHW ------------
__global__ __launch_bounds__(256) void make_quantized(const float* __restrict__ zt,
                                                      const float* __restrict__ res,
                                                      float* __restrict__ q) {
  __shared__ float t[32][33];
  int b = blockIdx.z, c0 = blockIdx.y*32, hw0 = blockIdx.x*32;
  for (int i = threadIdx.x; i < 1024; i += 256) {
    int tt = i >> 5, cc = i & 31;
    long o = ((long)(b*4096 + hw0 + tt) << 8) + c0 + cc;
    t[cc][tt] = zt[o] - res[o];
  }
  __syncthreads();
  for (int i = threadIdx.x; i < 1024; i += 256) {
    int cc = i >> 5, ww = i & 31;
    q[((long)(b*256 + c0 + cc) << 12) + hw0 + ww] = t[cc][ww];
  }
}

// ---------------- one residual-VQ level: fused GEMM + argmin + update -------
// block = 64 tokens; k in chunks of 64, c in chunks of 64; XOR-swizzled LDS
// tiles for conflict-free float4 reads. First-index tie-break (jnp.argmin).
__global__ __launch_bounds__(256) void vq_level(
    const float* __restrict__ cb, const float* __restrict__ cbn,
    float* __restrict__ res, float* __restrict__ idx_out,
    float* __restrict__ loss_out)
{
  __shared__ float s_a[4096];
  __shared__ float s_b[4096];
  __shared__ float s_d[64*65];
  __shared__ float s_rv[256];
  __shared__ int   s_ri[256];
  __shared__ float s_min[64];
  __shared__ int   s_mini[64];
  const int tid = threadIdx.x;
  const long t0 = (long)blockIdx.x * 64;
  const int tg = tid & 15, kg = tid >> 4;
  if (tid < 64) { s_min[tid] = 3.4e38f; s_mini[tid] = 0; }

  for (int k0 = 0; k0 < 1024; k0 += 64) {
    float acc[4][4];
#pragma unroll
    for (int i = 0; i < 4; ++i)
#pragma unroll
      for (int j = 0; j < 4; ++j) acc[i][j] = 0.f;

    for (int cs = 0; cs < 256; cs += 64) {
      __syncthreads();
      for (int i = tid; i < 4096; i += 256) {
        int t = i >> 6, c = i & 63;
        int sw = ((t >> 2) & 7) << 2;
        s_a[(t << 6) + (c ^ sw)] = res[((t0 + t) << 8) + cs + c];
        s_b[(t << 6) + (c ^ sw)] = cb[((long)(k0 + t) << 8) + cs + c];
      }
      __syncthreads();
      const int swa = (tg & 7) << 2;
      const int swb = (kg & 7) << 2;
#pragma unroll 4
      for (int c0 = 0; c0 < 64; c0 += 4) {
        float4 ra[4], rb[4];
#pragma unroll
        for (int i = 0; i < 4; ++i)
          ra[i] = *(const float4*)&s_a[((tg*4 + i) << 6) + (c0 ^ swa)];
#pragma unroll
        for (int j = 0; j < 4; ++j)
          rb[j] = *(const float4*)&s_b[((kg*4 + j) << 6) + (c0 ^ swb)];
#pragma unroll
        for (int i = 0; i < 4; ++i)
#pragma unroll
          for (int j = 0; j < 4; ++j) {
            acc[i][j] = fmaf(ra[i].x, rb[j].x, acc[i][j]);
            acc[i][j] = fmaf(ra[i].y, rb[j].y, acc[i][j]);
            acc[i][j] = fmaf(ra[i].z, rb[j].z, acc[i][j]);
            acc[i][j] = fmaf(ra[i].w, rb[j].w, acc[i][j]);
          }
      }
    }
    // distances for this k-chunk
#pragma unroll
    for (int i = 0; i < 4; ++i)
#pragma unroll
      for (int j = 0; j < 4; ++j)
        s_d[(tg*4 + i)*65 + kg*4 + j] = cbn[k0 + kg*4 + j] - 2.f*acc[i][j];
    __syncthreads();
    // per-token min over 64 k: 4 threads/token then merge (k-ascending ties)
    {
      int tt = tid >> 2, q = tid & 3;
      float mv = 3.4e38f; int mi = 0;
#pragma unroll
      for (int m = 0; m < 16; ++m) {
        int k = q*16 + m;
        float dv = s_d[tt*65 + k];
        if (dv < mv) { mv = dv; mi = k; }
      }
      s_rv[tid] = mv; s_ri[tid] = mi;
    }
    __syncthreads();
    if (tid < 64) {
      float mv = s_rv[tid*4]; int mi = s_ri[tid*4];
#pragma unroll
      for (int q = 1; q < 4; ++q) {
        float v = s_rv[tid*4 + q];
        if (v < mv) { mv = v; mi = s_ri[tid*4 + q]; }
      }
      if (mv < s_min[tid]) { s_min[tid] = mv; s_mini[tid] = k0 + mi; }
    }
    __syncthreads();
  }
  __syncthreads();

  // residual update + commit loss (= mean(new_residual^2))
  float lsum = 0.f;
  for (int m = 0; m < 64; ++m) {
    int w = s_mini[m];
    long ro = ((t0 + m) << 8) + tid;
    float nv = res[ro] - cb[((long)w << 8) + tid];
    res[ro] = nv;
    lsum += nv*nv;
  }
  for (int off = 32; off; off >>= 1) lsum += __shfl_down(lsum, off, 64);
  __syncthreads();
  if ((tid & 63) == 0) s_rv[tid >> 6] = lsum;
  __syncthreads();
  if (tid == 0) {
    float tot = s_rv[0] + s_rv[1] + s_rv[2] + s_rv[3];
    atomicAdd(loss_out, tot * (1.f/(65536.f*256.f)));
  }
  if (tid < 64) {
    long tglob = t0 + tid;
    int b = (int)(tglob >> 12), hw = (int)(tglob & 4095);
    idx_out[(long)b*16384 + hw] = (float)s_mini[tid];
  }
}

// ---------------------------------------------------------------------------
extern "C" void kernel_launch(void* const* d_in, const int* in_sizes, int n_in,
                              void* d_out, int out_size, void* d_ws, size_t ws_size,
                              hipStream_t stream) {
  const float* x      = (const float*)d_in[0];
  const float* ew1    = (const float*)d_in[1];
  const float* eb1    = (const float*)d_in[2];
  const float* ew2    = (const float*)d_in[3];
  const float* eb2    = (const float*)d_in[4];
  const float* ew3    = (const float*)d_in[5];
  const float* eb3    = (const float*)d_in[6];
  const float* ew4    = (const float*)d_in[7];
  const float* eb4    = (const float*)d_in[8];
  const float* cbooks = (const float*)d_in[9];
  const float* dw1    = (const float*)d_in[10];
  const float* db1    = (const float*)d_in[11];
  const float* dw2    = (const float*)d_in[12];
  const float* db2    = (const float*)d_in[13];
  const float* dw3    = (const float*)d_in[14];
  const float* db3    = (const float*)d_in[15];
  const float* dw4    = (const float*)d_in[16];
  const float* db4    = (const float*)d_in[17];

  float* out = (float*)d_out;
  float* o_recon = out;                  // (16,3,512,512)
  float* o_idx   = out + 12582912;       // (16,4,64,64)
  float* o_loss  = out + 12845056;       // (4,)
  float* o_q     = out + 12845060;       // (16,256,64,64)

  float* ws  = (float*)d_ws;
  float* h1  = ws;                       // 16,777,216
  float* h2  = ws + 16777216;            //  8,388,608
  float* h3  = ws + 25165824;            // 16,777,216
  float* z   = h1;                       // reuse (h1 dead)
  float* zt  = h3;                       // reuse (h3 dead)
  float* res = ws + 41943040;            // 16,777,216
  float* d1  = ws + 16777216;            // reuse h2 region
  float* d2  = ws;                       // reuse F0
  float* d3  = ws + 16777216;            // 67,108,864 (d1/zt/res dead by then)
  float* wp2 = ws + 83886080;            // 131,072
  float* wp3 = wp2 + 131072;             //  65,536
  float* wp4 = wp3 + 65536;              //   3,072
  float* cbn = wp4 + 3072;               //   4,096

  // independent prep
  rearrange_convT<<<256, 256, 0, stream>>>(dw2, wp2, 128, 64);
  rearrange_convT<<<256, 256, 0, stream>>>(dw3, wp3, 64, 64);
  rearrange_convT<<<16, 256, 0, stream>>>(dw4, wp4, 64, 3);
  cb_norm<<<4096, 256, 0, stream>>>(cbooks, cbn);
  zero4<<<1, 64, 0, stream>>>(o_loss);

  // encoder
  conv_tiled<64,8,8,4,4,2,1><<<dim3(256,1,16), 256, 0, stream>>>(
      x, ew1, eb1, h1, 16, 3, 256, 256, 64, 16, 1, 1,
      0L, 1048576L, 16384L, 128L, 1L);
  conv_tiled<64,8,8,4,4,2,1><<<dim3(64,2,16), 256, 0, stream>>>(
      h1, ew2, eb2, h2, 16, 64, 128, 128, 128, 8, 1, 1,
      0L, 524288L, 4096L, 64L, 1L);
  conv_tiled<64,8,8,3,3,1,1><<<dim3(64,4,16), 256, 0, stream>>>(
      h2, ew3, eb3, h3, 16, 128, 64, 64, 256, 8, 1, 1,
      0L, 1048576L, 4096L, 64L, 1L);
  conv_tiled<64,8,8,3,3,1,0><<<dim3(64,4,16), 256, 0, stream>>>(
      h3, ew4, eb4, z, 16, 256, 64, 64, 256, 8, 1, 1,
      0L, 1048576L, 4096L, 64L, 1L);

  // VQ
  transpose_zt<<<dim3(128,8,16), 256, 0, stream>>>(z, zt, res);
  for (int l = 0; l < 4; ++l)
    vq_level<<<1024, 256, 0, stream>>>(cbooks + (long)l*262144, cbn + l*1024,
                                       res, o_idx + l*4096, o_loss + l);
  make_quantized<<<dim3(128,8,16), 256, 0, stream>>>(zt, res, o_q);

  // decoder
  conv_tiled<64,8,8,3,3,1,1><<<dim3(64,2,16), 256, 0, stream>>>(
      o_q, dw1, db1, d1, 16, 256, 64, 64, 128, 8, 1, 1,
      0L, 524288L, 4096L, 64L, 1L);
  for (int p = 0; p < 4; ++p) {
    int py = p >> 1, px = p & 1;
    conv_tiled<64,8,8,2,2,1,1><<<dim3(64,1,16), 256, 0, stream>>>(
        d1, wp2 + p*32768, db2, d2, 16, 128, 64, 64, 64, 8, 1-py, 1-px,
        (long)(py*128 + px), 1048576L, 16384L, 256L, 2L);
  }
  for (int p = 0; p < 4; ++p) {
    int py = p >> 1, px = p & 1;
    conv_tiled<64,8,8,2,2,1,1><<<dim3(256,1,16), 256, 0, stream>>>(
        d2, wp3 + p*16384, db3, d3, 16, 64, 128, 128, 64, 16, 1-py, 1-px,
        (long)(py*256 + px), 4194304L, 65536L, 512L, 2L);
  }
  for (int p = 0; p < 4; ++p) {
    int py = p >> 1, px = p & 1;
    conv_tiled<4,16,16,2,2,1,2><<<dim3(256,1,16), 256, 0, stream>>>(
        d3, wp4 + p*768, db4, o_recon, 16, 64, 256, 256, 3, 16, 1-py, 1-px,
        (long)(py*512 + px), 786432L, 262144L, 1024L, 2L);
  }
  (void)in_sizes; (void)n_in; (void)out_size; (void)ws_size;
}